// Round 3
// baseline (570.236 us; speedup 1.0000x reference)
//
#include <hip/hip_runtime.h>
#include <hip/hip_bf16.h>

typedef __attribute__((ext_vector_type(4))) float f32x4;
typedef __attribute__((ext_vector_type(8))) short bf16x8;

constexpr int NB = 16, NN = 2048, NS = 4, NDIM = 512, NH = 8, NDS = 64;
constexpr float LOG2PI = 1.8378770664093453f;
constexpr float INV_SQRT_DIM = 0.04419417382415922f;  // 1/sqrt(512)

__device__ inline short f2bf(float f) {           // hardware RNE via v_cvt (pairs to v_cvt_pk_bf16_f32)
  __hip_bfloat16 h = __float2bfloat16(f);
  return *reinterpret_cast<short*>(&h);
}
__device__ inline float bf2f(short b) {
  union { unsigned u; float f; } v;
  v.u = ((unsigned)(unsigned short)b) << 16;
  return v.f;
}

// ---------------------------------------------------------------------------
// Fused K+V projection GEMM: for rows r=(b*2048+n)*4+s (131072), cols j=0..511
//   Ck = X @ Wk^T (+bk in epilogue) -> GMM log-likelihood reduce -> ll_ws
//   Cv = X @ Wv^T (+bv in epilogue) -> bf16 V in [g=(b*4+s)*8+h][n][d]
// Tile 128x128, BK=64, 4 waves (2x2), wave tile 64x64 (one head wide).
// A tile staged ONCE, used for both matmuls. LDS XOR-swizzled (row&7)<<4.
// ---------------------------------------------------------------------------
__global__ __launch_bounds__(256) void projkv_kernel(
    const float* __restrict__ X,
    const float* __restrict__ Wk, const float* __restrict__ bkp,
    const float* __restrict__ Wv, const float* __restrict__ bvp,
    const float* __restrict__ Mp, const float* __restrict__ Sp,
    const float* __restrict__ pp,
    float* __restrict__ ll_ws, short* __restrict__ v_ws)
{
  __shared__ short As[128 * 64];    // 16 KB, [row][64] bf16, 128 B rows, swizzled
  __shared__ short Bks[128 * 64];
  __shared__ short Bvs[128 * 64];

  // XCD-chunked remap (bijective, 4096 % 8 == 0): blocks sharing an mt row-tile
  // get consecutive work ids on the SAME XCD -> X tile L2-resident across ct.
  const int bid0 = blockIdx.x;
  const int bid = (bid0 & 7) * 512 + (bid0 >> 3);
  const int ct = bid & 3;        // col tile 0..3
  const int mt = bid >> 2;       // row tile 0..1023
  const int m0 = mt * 128;
  const int c0 = ct * 128;
  const int t = threadIdx.x;
  const int l = t & 63;
  const int w = t >> 6;
  const int wr = w >> 1, wc = w & 1;
  const int lg = l >> 4, lr = l & 15;

  f32x4 ak[4][4] = {};
  f32x4 av[4][4] = {};

  const int srr = t >> 4;        // staging row within 16-row pass
  const int skv = t & 15;        // float4 index within 64-float k-slice

  for (int k0 = 0; k0 < NDIM; k0 += 64) {
    __syncthreads();             // previous compute done before overwrite
    #pragma unroll
    for (int pass = 0; pass < 8; ++pass) {
      const int row = pass * 16 + srr;
      const int wb = (row * 128 + skv * 8) ^ ((row & 7) << 4);  // swizzled byte
      const float4 xa = *reinterpret_cast<const float4*>(
          &X[(size_t)(m0 + row) * NDIM + k0 + skv * 4]);
      const float4 ka = *reinterpret_cast<const float4*>(
          &Wk[(size_t)(c0 + row) * NDIM + k0 + skv * 4]);
      const float4 va = *reinterpret_cast<const float4*>(
          &Wv[(size_t)(c0 + row) * NDIM + k0 + skv * 4]);
      short4 s;
      s.x = f2bf(xa.x); s.y = f2bf(xa.y); s.z = f2bf(xa.z); s.w = f2bf(xa.w);
      *reinterpret_cast<short4*>((char*)As + wb) = s;
      s.x = f2bf(ka.x); s.y = f2bf(ka.y); s.z = f2bf(ka.z); s.w = f2bf(ka.w);
      *reinterpret_cast<short4*>((char*)Bks + wb) = s;
      s.x = f2bf(va.x); s.y = f2bf(va.y); s.z = f2bf(va.z); s.w = f2bf(va.w);
      *reinterpret_cast<short4*>((char*)Bvs + wb) = s;
    }
    __syncthreads();
    #pragma unroll
    for (int kk = 0; kk < 64; kk += 32) {
      bf16x8 a[4], bkf[4], bvf[4];
      #pragma unroll
      for (int i = 0; i < 4; ++i) {
        const int r = wr * 64 + i * 16 + lr;
        const int byte = (r * 128 + (kk + lg * 8) * 2) ^ ((r & 7) << 4);
        a[i] = *reinterpret_cast<const bf16x8*>((const char*)As + byte);
      }
      #pragma unroll
      for (int j = 0; j < 4; ++j) {
        const int r = wc * 64 + j * 16 + lr;
        const int byte = (r * 128 + (kk + lg * 8) * 2) ^ ((r & 7) << 4);
        bkf[j] = *reinterpret_cast<const bf16x8*>((const char*)Bks + byte);
        bvf[j] = *reinterpret_cast<const bf16x8*>((const char*)Bvs + byte);
      }
      #pragma unroll
      for (int i = 0; i < 4; ++i) {
        #pragma unroll
        for (int j = 0; j < 4; ++j) {
          ak[i][j] = __builtin_amdgcn_mfma_f32_16x16x32_bf16(a[i], bkf[j], ak[i][j], 0, 0, 0);
          av[i][j] = __builtin_amdgcn_mfma_f32_16x16x32_bf16(a[i], bvf[j], av[i][j], 0, 0, 0);
        }
      }
    }
  }

  // C/D frag mapping: col = lane&15 (lr), row = 4*(lane>>4) + e within each 16-block.
  // Global row R = m0 + wr*64 + i*16 + 4*lg + e -> base multiple of 4, so seed s == e.

  // ---- K epilogue: GMM log-likelihood ----
  {
    const float p0 = pp[0], p1 = pp[1], p2 = pp[2], p3 = pp[3];
    const float pmx = fmaxf(fmaxf(p0, p1), fmaxf(p2, p3));
    const float lse = pmx + logf(expf(p0 - pmx) + expf(p1 - pmx) + expf(p2 - pmx) + expf(p3 - pmx));
    const float lp[4] = {p0 - lse, p1 - lse, p2 - lse, p3 - lse};

    float part[4][4];
    #pragma unroll
    for (int i = 0; i < 4; ++i)
      #pragma unroll
      for (int e = 0; e < 4; ++e) part[i][e] = 0.f;

    #pragma unroll
    for (int j = 0; j < 4; ++j) {
      const int Jg = c0 + wc * 64 + j * 16 + lr;
      const float bj = bkp[Jg];
      #pragma unroll
      for (int e = 0; e < 4; ++e) {
        const float sv = Sp[e * NDIM + Jg];
        const float sig = log1pf(expf(sv));       // softplus
        const float mu = Mp[e * NDIM + Jg];
        const float cc = -0.5f * LOG2PI - logf(sig);
        const float i2 = 0.5f / (sig * sig);
        #pragma unroll
        for (int i = 0; i < 4; ++i) {
          const float kv = ak[i][j][e] + bj;
          const float d = kv - mu;
          part[i][e] += cc - d * d * i2;
        }
      }
    }
    #pragma unroll
    for (int off = 1; off < 16; off <<= 1) {
      #pragma unroll
      for (int i = 0; i < 4; ++i)
        #pragma unroll
        for (int e = 0; e < 4; ++e)
          part[i][e] += __shfl_xor(part[i][e], off, 64);
    }
    if (lr == 0) {
      const int h = ct * 2 + wc;
      #pragma unroll
      for (int i = 0; i < 4; ++i) {
        #pragma unroll
        for (int e = 0; e < 4; ++e) {
          const int R = m0 + wr * 64 + i * 16 + 4 * lg + e;
          const int bn = R >> 2;               // b*2048 + n
          const int bb = bn >> 11;
          const int nn = bn & (NN - 1);
          ll_ws[((size_t)((bb * NS + e) * NH + h)) * NN + nn] =
              (part[i][e] + lp[e]) * INV_SQRT_DIM;
        }
      }
    }
  }

  // ---- V epilogue: bf16 V in [g][n][d] ----
  {
    #pragma unroll
    for (int j = 0; j < 4; ++j) {
      const int Jg = c0 + wc * 64 + j * 16 + lr;
      const float bj = bvp[Jg];
      const int h = Jg >> 6;
      const int d = Jg & 63;
      #pragma unroll
      for (int i = 0; i < 4; ++i) {
        #pragma unroll
        for (int e = 0; e < 4; ++e) {
          const int R = m0 + wr * 64 + i * 16 + 4 * lg + e;
          const int bn = R >> 2;
          const int bb = bn >> 11;
          const int nn = bn & (NN - 1);
          v_ws[((size_t)((bb * NS + e) * NH + h) * NN + nn) * NDS + d] =
              f2bf(av[i][j][e] + bj);
        }
      }
    }
  }
}

// ---------------------------------------------------------------------------
// Pooling: per g=(b*4+s)*8+h : A = softmax(ll[g,:]), O0[g,d] = mu + sum_n A_n V[g,n,d]
// ---------------------------------------------------------------------------
__global__ __launch_bounds__(256) void pool_kernel(
    const float* __restrict__ ll_ws, const short* __restrict__ v_ws,
    const float* __restrict__ Mp, float* __restrict__ O0)
{
  __shared__ float Al[NN];
  __shared__ float red[4][NDS];
  __shared__ float sred[8];
  const int g = blockIdx.x;
  const int t = threadIdx.x;
  const int w = t >> 6, l = t & 63;
  const float* ll = ll_ws + (size_t)g * NN;

  float v8[8];
  float mx = -1e30f;
  #pragma unroll
  for (int i = 0; i < 8; ++i) { v8[i] = ll[t + i * 256]; mx = fmaxf(mx, v8[i]); }
  #pragma unroll
  for (int off = 1; off < 64; off <<= 1) mx = fmaxf(mx, __shfl_xor(mx, off, 64));
  if (l == 0) sred[w] = mx;
  __syncthreads();
  mx = fmaxf(fmaxf(sred[0], sred[1]), fmaxf(sred[2], sred[3]));

  float sum = 0.f;
  #pragma unroll
  for (int i = 0; i < 8; ++i) {
    const float e = expf(v8[i] - mx);
    Al[t + i * 256] = e;
    sum += e;
  }
  #pragma unroll
  for (int off = 1; off < 64; off <<= 1) sum += __shfl_xor(sum, off, 64);
  __syncthreads();
  if (l == 0) sred[4 + w] = sum;
  __syncthreads();
  const float lsum = sred[4] + sred[5] + sred[6] + sred[7];

  const short* vp = v_ws + (size_t)g * ((size_t)NN * NDS) + l;
  float acc = 0.f;
  #pragma unroll 8
  for (int i = 0; i < 512; ++i) {
    const int n = (w << 9) + i;
    acc += Al[n] * bf2f(vp[(size_t)n * NDS]);
  }
  red[w][l] = acc;
  __syncthreads();
  if (w == 0) {
    const float tot = red[0][l] + red[1][l] + red[2][l] + red[3][l];
    const int s = (g >> 3) & 3, h = g & 7;
    O0[(size_t)g * NDS + l] = Mp[s * NDIM + h * NDS + l] + tot / lsum;
  }
}

// ---------------------------------------------------------------------------
// BatchNorm1d (training mode, biased var, eps=1e-5) over B=16 per feature f.
// ---------------------------------------------------------------------------
__global__ __launch_bounds__(256) void bn_kernel(
    const float* __restrict__ Xin, const float* __restrict__ gg,
    const float* __restrict__ bb, float* __restrict__ Yo)
{
  const int f = blockIdx.x * 256 + threadIdx.x;  // 0..2047
  float x[NB];
  float m = 0.f;
  #pragma unroll
  for (int b = 0; b < NB; ++b) { x[b] = Xin[b * (NS * NDIM) + f]; m += x[b]; }
  m *= (1.f / NB);
  float v = 0.f;
  #pragma unroll
  for (int b = 0; b < NB; ++b) { const float d = x[b] - m; v += d * d; }
  v *= (1.f / NB);
  const float inv = rsqrtf(v + 1e-5f) * gg[f];
  const float bf = bb[f];
  #pragma unroll
  for (int b = 0; b < NB; ++b) Yo[b * (NS * NDIM) + f] = (x[b] - m) * inv + bf;
}

// ---------------------------------------------------------------------------
// Z = Y + relu(Y @ Wo^T + bo), rows = 64, cols = 512
// ---------------------------------------------------------------------------
__global__ __launch_bounds__(256) void mlp_kernel(
    const float* __restrict__ Yi, const float* __restrict__ Wo,
    const float* __restrict__ bo, float* __restrict__ Zo)
{
  const int idx = blockIdx.x * 256 + threadIdx.x;  // 0..32767
  const int r = idx >> 9, j = idx & 511;
  const float4* yr = reinterpret_cast<const float4*>(Yi + (size_t)r * NDIM);
  const float4* wrow = reinterpret_cast<const float4*>(Wo + (size_t)j * NDIM);
  float acc = 0.f;
  #pragma unroll 4
  for (int i = 0; i < NDIM / 4; ++i) {
    const float4 a = yr[i], b = wrow[i];
    acc += a.x * b.x + a.y * b.y + a.z * b.z + a.w * b.w;
  }
  const float rl = acc + bo[j];
  Zo[idx] = Yi[idx] + fmaxf(rl, 0.f);
}

extern "C" void kernel_launch(void* const* d_in, const int* in_sizes, int n_in,
                              void* d_out, int out_size, void* d_ws, size_t ws_size,
                              hipStream_t stream) {
  (void)in_sizes; (void)n_in; (void)out_size; (void)ws_size;
  const float* X  = (const float*)d_in[0];
  const float* M  = (const float*)d_in[1];
  const float* S  = (const float*)d_in[2];
  const float* p  = (const float*)d_in[3];
  const float* Wk = (const float*)d_in[4];
  const float* bk = (const float*)d_in[5];
  const float* Wv = (const float*)d_in[6];
  const float* bv = (const float*)d_in[7];
  const float* Wo = (const float*)d_in[8];
  const float* bo = (const float*)d_in[9];
  const float* g0 = (const float*)d_in[10];
  const float* b0 = (const float*)d_in[11];
  const float* g1 = (const float*)d_in[12];
  const float* b1 = (const float*)d_in[13];

  char* ws = (char*)d_ws;
  short* v_ws  = (short*)ws;                                    // 128 MiB bf16 V
  float* ll_ws = (float*)(ws + (size_t)134217728);              // 4 MiB logits
  float* O0    = (float*)(ws + (size_t)134217728 + 4194304);    // 128 KiB
  float* Y     = O0 + 32768;                                    // 128 KiB
  float* Z     = Y + 32768;                                     // 128 KiB

  projkv_kernel<<<4096, 256, 0, stream>>>(X, Wk, bk, Wv, bv, M, S, p, ll_ws, v_ws);
  pool_kernel<<<512, 256, 0, stream>>>(ll_ws, v_ws, M, O0);
  bn_kernel<<<8, 256, 0, stream>>>(O0, g0, b0, Y);
  mlp_kernel<<<128, 256, 0, stream>>>(Y, Wo, bo, Z);
  bn_kernel<<<8, 256, 0, stream>>>(Z, g1, b1, (float*)d_out);
}

// Round 4
// 483.434 us; speedup vs baseline: 1.1796x; 1.1796x over previous
//
#include <hip/hip_runtime.h>
#include <hip/hip_bf16.h>

typedef __attribute__((ext_vector_type(4))) float f32x4;
typedef __attribute__((ext_vector_type(8))) short bf16x8;

constexpr int NB = 16, NN = 2048, NS = 4, NDIM = 512, NH = 8, NDS = 64;
constexpr float LOG2PI = 1.8378770664093453f;
constexpr float INV_SQRT_DIM = 0.04419417382415922f;  // 1/sqrt(512)

__device__ inline short f2bf(float f) {           // hardware RNE (v_cvt_pk_bf16_f32 pairs)
  __hip_bfloat16 h = __float2bfloat16(f);
  return *reinterpret_cast<short*>(&h);
}
__device__ inline float bf2f(short b) {
  union { unsigned u; float f; } v;
  v.u = ((unsigned)(unsigned short)b) << 16;
  return v.f;
}

__device__ inline void gld16(const void* g, void* l) {
  __builtin_amdgcn_global_load_lds(
      (const __attribute__((address_space(1))) void*)g,
      (__attribute__((address_space(3))) void*)l, 16, 0, 0);
}

// ---------------------------------------------------------------------------
// fp32 -> bf16 conversion, grid-stride, 8 elems/thread/iter (16B stores)
// ---------------------------------------------------------------------------
__global__ __launch_bounds__(256) void cvtx_kernel(
    const float* __restrict__ in, short* __restrict__ out, int n8)
{
  const int stride = gridDim.x * blockDim.x;
  for (int i = blockIdx.x * blockDim.x + threadIdx.x; i < n8; i += stride) {
    const float4 a = reinterpret_cast<const float4*>(in)[(size_t)i * 2];
    const float4 b = reinterpret_cast<const float4*>(in)[(size_t)i * 2 + 1];
    bf16x8 o;
    o[0] = f2bf(a.x); o[1] = f2bf(a.y); o[2] = f2bf(a.z); o[3] = f2bf(a.w);
    o[4] = f2bf(b.x); o[5] = f2bf(b.y); o[6] = f2bf(b.z); o[7] = f2bf(b.w);
    *reinterpret_cast<bf16x8*>(&out[(size_t)i * 8]) = o;
  }
}

// Convert both weight matrices (512x512 each) in one launch.
__global__ __launch_bounds__(256) void cvtw_kernel(
    const float* __restrict__ wk, const float* __restrict__ wv,
    short* __restrict__ wkb, short* __restrict__ wvb)
{
  const int i = blockIdx.x * blockDim.x + threadIdx.x;  // 0..65535
  const float* src = (i < 32768) ? wk : wv;
  short* dst = (i < 32768) ? wkb : wvb;
  const int j = i & 32767;
  const float4 a = reinterpret_cast<const float4*>(src)[(size_t)j * 2];
  const float4 b = reinterpret_cast<const float4*>(src)[(size_t)j * 2 + 1];
  bf16x8 o;
  o[0] = f2bf(a.x); o[1] = f2bf(a.y); o[2] = f2bf(a.z); o[3] = f2bf(a.w);
  o[4] = f2bf(b.x); o[5] = f2bf(b.y); o[6] = f2bf(b.z); o[7] = f2bf(b.w);
  *reinterpret_cast<bf16x8*>(&dst[(size_t)j * 8]) = o;
}

// ---------------------------------------------------------------------------
// Fused K+V projection GEMM (bf16 MFMA), rows r=(b*2048+n)*4+s, cols j=0..511
//   K-path epilogue: GMM log-likelihood reduce -> ll_ws
//   V-path epilogue: bf16 V in [g=(b*4+s)*8+h][n][d]
// Tile 128x128, BK=64, 4 waves (2x2), wave tile 64x64 (one head wide).
// B tiles staged via global_load_lds (linear dest) with inverse-swizzled
// global source; reads use XOR-swizzle byte ^= (row&7)<<4  -> conflict-free.
// ABF16: A (X) also pre-converted bf16 and staged the same way.
// else : A reg-staged fp32->bf16 with swizzled ds_write (ws too small).
// ---------------------------------------------------------------------------
template<bool ABF16>
__global__ __launch_bounds__(256) void projkv_kernel(
    const void* __restrict__ Xp,
    const short* __restrict__ Wkb, const short* __restrict__ Wvb,
    const float* __restrict__ bkp, const float* __restrict__ bvp,
    const float* __restrict__ Mp, const float* __restrict__ Sp,
    const float* __restrict__ pp,
    float* __restrict__ ll_ws, short* __restrict__ v_ws)
{
  __shared__ short As[128 * 64];    // 16 KB each, [row][64] bf16, 128 B rows
  __shared__ short Bks[128 * 64];
  __shared__ short Bvs[128 * 64];

  // XCD-chunked bijective remap (4096 % 8 == 0): the 4 ct-blocks of one mt
  // row-tile land on one XCD -> X tile L2-resident.
  const int bid0 = blockIdx.x;
  const int bid = (bid0 & 7) * 512 + (bid0 >> 3);
  const int ct = bid & 3;
  const int mt = bid >> 2;
  const int m0 = mt * 128;
  const int c0 = ct * 128;
  const int t = threadIdx.x;
  const int l = t & 63;
  const int w = t >> 6;
  const int wr = w >> 1, wc = w & 1;
  const int lg = l >> 4, lr = l & 15;

  f32x4 ak[4][4] = {};
  f32x4 av[4][4] = {};

  const int srr = t >> 4;        // (mixed path) staging row within 16-row pass
  const int skv = t & 15;        // (mixed path) float4 index in 64-float slice
  const int g8 = (l & 7) ^ (l >> 3);  // inverse-swizzled source column group

  for (int k0 = 0; k0 < NDIM; k0 += 64) {
    __syncthreads();             // all waves done reading LDS before overwrite
    if constexpr (ABF16) {
      const short* Xb = (const short*)Xp;
      #pragma unroll
      for (int q = 0; q < 4; ++q) {
        const int r0 = w * 32 + q * 8;
        gld16(&Xb[(size_t)(m0 + r0 + (l >> 3)) * NDIM + k0 + g8 * 8],
              (char*)As + r0 * 128);
      }
    } else {
      const float* Xf = (const float*)Xp;
      #pragma unroll
      for (int pass = 0; pass < 8; ++pass) {
        const int row = pass * 16 + srr;
        const int wb = (row * 128 + skv * 8) ^ ((row & 7) << 4);
        const float4 xa = *reinterpret_cast<const float4*>(
            &Xf[(size_t)(m0 + row) * NDIM + k0 + skv * 4]);
        short4 s;
        s.x = f2bf(xa.x); s.y = f2bf(xa.y); s.z = f2bf(xa.z); s.w = f2bf(xa.w);
        *reinterpret_cast<short4*>((char*)As + wb) = s;
      }
    }
    #pragma unroll
    for (int q = 0; q < 4; ++q) {
      const int r0 = w * 32 + q * 8;
      const size_t gi = (size_t)(c0 + r0 + (l >> 3)) * NDIM + k0 + g8 * 8;
      gld16(&Wkb[gi], (char*)Bks + r0 * 128);
      gld16(&Wvb[gi], (char*)Bvs + r0 * 128);
    }
    __syncthreads();             // compiler drains vmcnt+lgkmcnt here

    #pragma unroll
    for (int kk = 0; kk < 64; kk += 32) {
      bf16x8 a[4], bkf[4], bvf[4];
      #pragma unroll
      for (int i = 0; i < 4; ++i) {
        const int r = wr * 64 + i * 16 + lr;
        const int byte = (r * 128 + (kk + lg * 8) * 2) ^ ((r & 7) << 4);
        a[i] = *reinterpret_cast<const bf16x8*>((const char*)As + byte);
      }
      #pragma unroll
      for (int j = 0; j < 4; ++j) {
        const int r = wc * 64 + j * 16 + lr;
        const int byte = (r * 128 + (kk + lg * 8) * 2) ^ ((r & 7) << 4);
        bkf[j] = *reinterpret_cast<const bf16x8*>((const char*)Bks + byte);
        bvf[j] = *reinterpret_cast<const bf16x8*>((const char*)Bvs + byte);
      }
      #pragma unroll
      for (int i = 0; i < 4; ++i) {
        #pragma unroll
        for (int j = 0; j < 4; ++j) {
          ak[i][j] = __builtin_amdgcn_mfma_f32_16x16x32_bf16(a[i], bkf[j], ak[i][j], 0, 0, 0);
          av[i][j] = __builtin_amdgcn_mfma_f32_16x16x32_bf16(a[i], bvf[j], av[i][j], 0, 0, 0);
        }
      }
    }
  }

  // C/D frag mapping: col = lane&15 (lr), row = 4*(lane>>4)+e per 16-block.
  // Global row R = m0 + wr*64 + i*16 + 4*lg + e -> seed s == e (base % 4 == 0).

  // ---- K epilogue: GMM log-likelihood ----
  {
    const float p0 = pp[0], p1 = pp[1], p2 = pp[2], p3 = pp[3];
    const float pmx = fmaxf(fmaxf(p0, p1), fmaxf(p2, p3));
    const float lse = pmx + logf(expf(p0 - pmx) + expf(p1 - pmx) + expf(p2 - pmx) + expf(p3 - pmx));
    const float lp[4] = {p0 - lse, p1 - lse, p2 - lse, p3 - lse};

    float part[4][4];
    #pragma unroll
    for (int i = 0; i < 4; ++i)
      #pragma unroll
      for (int e = 0; e < 4; ++e) part[i][e] = 0.f;

    #pragma unroll
    for (int j = 0; j < 4; ++j) {
      const int Jg = c0 + wc * 64 + j * 16 + lr;
      const float bj = bkp[Jg];
      #pragma unroll
      for (int e = 0; e < 4; ++e) {
        const float sv = Sp[e * NDIM + Jg];
        const float sig = log1pf(expf(sv));       // softplus
        const float mu = Mp[e * NDIM + Jg];
        const float cc = -0.5f * LOG2PI - logf(sig);
        const float i2 = 0.5f / (sig * sig);
        #pragma unroll
        for (int i = 0; i < 4; ++i) {
          const float kv = ak[i][j][e] + bj;
          const float d = kv - mu;
          part[i][e] += cc - d * d * i2;
        }
      }
    }
    #pragma unroll
    for (int off = 1; off < 16; off <<= 1) {
      #pragma unroll
      for (int i = 0; i < 4; ++i)
        #pragma unroll
        for (int e = 0; e < 4; ++e)
          part[i][e] += __shfl_xor(part[i][e], off, 64);
    }
    if (lr == 0) {
      const int h = ct * 2 + wc;
      #pragma unroll
      for (int i = 0; i < 4; ++i) {
        #pragma unroll
        for (int e = 0; e < 4; ++e) {
          const int R = m0 + wr * 64 + i * 16 + 4 * lg + e;
          const int bn = R >> 2;               // b*2048 + n
          const int bb = bn >> 11;
          const int nn = bn & (NN - 1);
          ll_ws[((size_t)((bb * NS + e) * NH + h)) * NN + nn] =
              (part[i][e] + lp[e]) * INV_SQRT_DIM;
        }
      }
    }
  }

  // ---- V epilogue: bf16 V in [g][n][d] ----
  {
    #pragma unroll
    for (int j = 0; j < 4; ++j) {
      const int Jg = c0 + wc * 64 + j * 16 + lr;
      const float bj = bvp[Jg];
      const int h = Jg >> 6;
      const int d = Jg & 63;
      #pragma unroll
      for (int i = 0; i < 4; ++i) {
        #pragma unroll
        for (int e = 0; e < 4; ++e) {
          const int R = m0 + wr * 64 + i * 16 + 4 * lg + e;
          const int bn = R >> 2;
          const int bb = bn >> 11;
          const int nn = bn & (NN - 1);
          v_ws[((size_t)((bb * NS + e) * NH + h) * NN + nn) * NDS + d] =
              f2bf(av[i][j][e] + bj);
        }
      }
    }
  }
}

// ---------------------------------------------------------------------------
// Pooling: per g=(b*4+s)*8+h : A = softmax(ll[g,:]), O0[g,d] = mu + sum_n A_n V[g,n,d]
// ---------------------------------------------------------------------------
__global__ __launch_bounds__(256) void pool_kernel(
    const float* __restrict__ ll_ws, const short* __restrict__ v_ws,
    const float* __restrict__ Mp, float* __restrict__ O0)
{
  __shared__ float Al[NN];
  __shared__ float red[4][NDS];
  __shared__ float sred[8];
  const int g = blockIdx.x;
  const int t = threadIdx.x;
  const int w = t >> 6, l = t & 63;
  const float* ll = ll_ws + (size_t)g * NN;

  float v8[8];
  float mx = -1e30f;
  #pragma unroll
  for (int i = 0; i < 8; ++i) { v8[i] = ll[t + i * 256]; mx = fmaxf(mx, v8[i]); }
  #pragma unroll
  for (int off = 1; off < 64; off <<= 1) mx = fmaxf(mx, __shfl_xor(mx, off, 64));
  if (l == 0) sred[w] = mx;
  __syncthreads();
  mx = fmaxf(fmaxf(sred[0], sred[1]), fmaxf(sred[2], sred[3]));

  float sum = 0.f;
  #pragma unroll
  for (int i = 0; i < 8; ++i) {
    const float e = expf(v8[i] - mx);
    Al[t + i * 256] = e;
    sum += e;
  }
  #pragma unroll
  for (int off = 1; off < 64; off <<= 1) sum += __shfl_xor(sum, off, 64);
  __syncthreads();
  if (l == 0) sred[4 + w] = sum;
  __syncthreads();
  const float lsum = sred[4] + sred[5] + sred[6] + sred[7];

  const short* vp = v_ws + (size_t)g * ((size_t)NN * NDS) + l;
  float acc = 0.f;
  #pragma unroll 8
  for (int i = 0; i < 512; ++i) {
    const int n = (w << 9) + i;
    acc += Al[n] * bf2f(vp[(size_t)n * NDS]);
  }
  red[w][l] = acc;
  __syncthreads();
  if (w == 0) {
    const float tot = red[0][l] + red[1][l] + red[2][l] + red[3][l];
    const int s = (g >> 3) & 3, h = g & 7;
    O0[(size_t)g * NDS + l] = Mp[s * NDIM + h * NDS + l] + tot / lsum;
  }
}

// ---------------------------------------------------------------------------
// BatchNorm1d (training mode, biased var, eps=1e-5) over B=16 per feature f.
// ---------------------------------------------------------------------------
__global__ __launch_bounds__(256) void bn_kernel(
    const float* __restrict__ Xin, const float* __restrict__ gg,
    const float* __restrict__ bb, float* __restrict__ Yo)
{
  const int f = blockIdx.x * 256 + threadIdx.x;  // 0..2047
  float x[NB];
  float m = 0.f;
  #pragma unroll
  for (int b = 0; b < NB; ++b) { x[b] = Xin[b * (NS * NDIM) + f]; m += x[b]; }
  m *= (1.f / NB);
  float v = 0.f;
  #pragma unroll
  for (int b = 0; b < NB; ++b) { const float d = x[b] - m; v += d * d; }
  v *= (1.f / NB);
  const float inv = rsqrtf(v + 1e-5f) * gg[f];
  const float bf = bb[f];
  #pragma unroll
  for (int b = 0; b < NB; ++b) Yo[b * (NS * NDIM) + f] = (x[b] - m) * inv + bf;
}

// ---------------------------------------------------------------------------
// Z = Y + relu(Y @ Wo^T + bo), rows = 64, cols = 512
// ---------------------------------------------------------------------------
__global__ __launch_bounds__(256) void mlp_kernel(
    const float* __restrict__ Yi, const float* __restrict__ Wo,
    const float* __restrict__ bo, float* __restrict__ Zo)
{
  const int idx = blockIdx.x * 256 + threadIdx.x;  // 0..32767
  const int r = idx >> 9, j = idx & 511;
  const float4* yr = reinterpret_cast<const float4*>(Yi + (size_t)r * NDIM);
  const float4* wrow = reinterpret_cast<const float4*>(Wo + (size_t)j * NDIM);
  float acc = 0.f;
  #pragma unroll 4
  for (int i = 0; i < NDIM / 4; ++i) {
    const float4 a = yr[i], b = wrow[i];
    acc += a.x * b.x + a.y * b.y + a.z * b.z + a.w * b.w;
  }
  const float rl = acc + bo[j];
  Zo[idx] = Yi[idx] + fmaxf(rl, 0.f);
}

extern "C" void kernel_launch(void* const* d_in, const int* in_sizes, int n_in,
                              void* d_out, int out_size, void* d_ws, size_t ws_size,
                              hipStream_t stream) {
  (void)in_sizes; (void)n_in; (void)out_size;
  const float* X  = (const float*)d_in[0];
  const float* M  = (const float*)d_in[1];
  const float* S  = (const float*)d_in[2];
  const float* p  = (const float*)d_in[3];
  const float* Wk = (const float*)d_in[4];
  const float* bk = (const float*)d_in[5];
  const float* Wv = (const float*)d_in[6];
  const float* bv = (const float*)d_in[7];
  const float* Wo = (const float*)d_in[8];
  const float* bo = (const float*)d_in[9];
  const float* g0 = (const float*)d_in[10];
  const float* b0 = (const float*)d_in[11];
  const float* g1 = (const float*)d_in[12];
  const float* b1 = (const float*)d_in[13];

  char* ws = (char*)d_ws;
  short* v_ws  = (short*)ws;                                    // 128 MiB bf16 V
  float* ll_ws = (float*)(ws + (size_t)134217728);              // 4 MiB logits
  float* O0    = (float*)(ws + (size_t)138412032);              // 128 KiB
  float* Y     = O0 + 32768;
  float* Z     = Y + 32768;
  short* Wkb   = (short*)(ws + (size_t)138805248);              // 512 KiB
  short* Wvb   = (short*)(ws + (size_t)139329536);              // 512 KiB
  short* Xb    = (short*)(ws + (size_t)139853824);              // 128 MiB (big path)
  const bool big = ws_size >= (size_t)139853824 + 134217728;

  cvtw_kernel<<<256, 256, 0, stream>>>(Wk, Wv, Wkb, Wvb);
  if (big) {
    cvtx_kernel<<<2048, 256, 0, stream>>>(X, Xb, 8388608);
    hipLaunchKernelGGL((projkv_kernel<true>), dim3(4096), dim3(256), 0, stream,
                       (const void*)Xb, Wkb, Wvb, bk, bv, M, S, p, ll_ws, v_ws);
  } else {
    hipLaunchKernelGGL((projkv_kernel<false>), dim3(4096), dim3(256), 0, stream,
                       (const void*)X, Wkb, Wvb, bk, bv, M, S, p, ll_ws, v_ws);
  }
  pool_kernel<<<512, 256, 0, stream>>>(ll_ws, v_ws, M, O0);
  bn_kernel<<<8, 256, 0, stream>>>(O0, g0, b0, Y);
  mlp_kernel<<<128, 256, 0, stream>>>(Y, Wo, bo, Z);
  bn_kernel<<<8, 256, 0, stream>>>(Z, g1, b1, (float*)d_out);
}

// Round 5
// 398.800 us; speedup vs baseline: 1.4299x; 1.2122x over previous
//
#include <hip/hip_runtime.h>
#include <hip/hip_bf16.h>

typedef __attribute__((ext_vector_type(4))) float f32x4;
typedef __attribute__((ext_vector_type(8))) short bf16x8;

constexpr int NB = 16, NN = 2048, NS = 4, NDIM = 512, NH = 8, NDS = 64;
constexpr float LOG2PI = 1.8378770664093453f;
constexpr float INV_SQRT_DIM = 0.04419417382415922f;  // 1/sqrt(512)

__device__ inline short f2bf(float f) {           // hardware RNE (v_cvt_pk_bf16_f32 pairs)
  __hip_bfloat16 h = __float2bfloat16(f);
  return *reinterpret_cast<short*>(&h);
}
__device__ inline float bf2f(short b) {
  union { unsigned u; float f; } v;
  v.u = ((unsigned)(unsigned short)b) << 16;
  return v.f;
}

__device__ inline void gld16(const void* g, void* l) {
  __builtin_amdgcn_global_load_lds(
      (const __attribute__((address_space(1))) void*)g,
      (__attribute__((address_space(3))) void*)l, 16, 0, 0);
}

// ---------------------------------------------------------------------------
// fp32 -> bf16 conversion, grid-stride, 8 elems/thread/iter (16B stores)
// ---------------------------------------------------------------------------
__global__ __launch_bounds__(256) void cvtx_kernel(
    const float* __restrict__ in, short* __restrict__ out, int n8)
{
  const int stride = gridDim.x * blockDim.x;
  for (int i = blockIdx.x * blockDim.x + threadIdx.x; i < n8; i += stride) {
    const float4 a = reinterpret_cast<const float4*>(in)[(size_t)i * 2];
    const float4 b = reinterpret_cast<const float4*>(in)[(size_t)i * 2 + 1];
    bf16x8 o;
    o[0] = f2bf(a.x); o[1] = f2bf(a.y); o[2] = f2bf(a.z); o[3] = f2bf(a.w);
    o[4] = f2bf(b.x); o[5] = f2bf(b.y); o[6] = f2bf(b.z); o[7] = f2bf(b.w);
    *reinterpret_cast<bf16x8*>(&out[(size_t)i * 8]) = o;
  }
}

// Convert both weight matrices (512x512 each) in one launch.
__global__ __launch_bounds__(256) void cvtw_kernel(
    const float* __restrict__ wk, const float* __restrict__ wv,
    short* __restrict__ wkb, short* __restrict__ wvb)
{
  const int i = blockIdx.x * blockDim.x + threadIdx.x;  // 0..65535
  const float* src = (i < 32768) ? wk : wv;
  short* dst = (i < 32768) ? wkb : wvb;
  const int j = i & 32767;
  const float4 a = reinterpret_cast<const float4*>(src)[(size_t)j * 2];
  const float4 b = reinterpret_cast<const float4*>(src)[(size_t)j * 2 + 1];
  bf16x8 o;
  o[0] = f2bf(a.x); o[1] = f2bf(a.y); o[2] = f2bf(a.z); o[3] = f2bf(a.w);
  o[4] = f2bf(b.x); o[5] = f2bf(b.y); o[6] = f2bf(b.z); o[7] = f2bf(b.w);
  *reinterpret_cast<bf16x8*>(&dst[(size_t)j * 8]) = o;
}

// ---------------------------------------------------------------------------
// Fused K+V projection GEMM (bf16 MFMA), 2-phase double-buffered pipeline.
// rows r=(b*2048+n)*4+s (131072), cols j=0..511
//   K-path epilogue: GMM log-likelihood reduce -> ll_ws
//   V-path epilogue: bf16 V in [g=(b*4+s)*8+h][n][d]
// Tile 128x128, BK=32, 16 K-steps, 4 waves (2x2), wave tile 64x64.
// LDS: 6 x 8KB (A/Bk/Bv double-buffered) = 48 KB -> 3 blocks/CU.
// Schedule (T3/T4 minimum 2-phase): STAGE(t+1) issued BEFORE compute(t);
// barrier waits vmcnt(6) (only next-tile loads outstanding) - current tile's
// loads had a full compute phase to land. Raw s_barrier, no full drain.
// Swizzle: 64B rows, 16B chunk cg ^= (row&3); involution applied on the
// gld_lds global SOURCE and the ds_read address (rule #21).
// ---------------------------------------------------------------------------
__global__ __launch_bounds__(256) void projkv2_kernel(
    const short* __restrict__ Xb,
    const short* __restrict__ Wkb, const short* __restrict__ Wvb,
    const float* __restrict__ bkp, const float* __restrict__ bvp,
    const float* __restrict__ Mp, const float* __restrict__ Sp,
    const float* __restrict__ pp,
    float* __restrict__ ll_ws, short* __restrict__ v_ws)
{
  __shared__ short As[2][128 * 32];
  __shared__ short Bks[2][128 * 32];
  __shared__ short Bvs[2][128 * 32];

  // XCD-chunked bijective remap (4096 % 8 == 0): 4 ct-blocks of one mt
  // row-tile land on one XCD -> X tile L2-resident.
  const int bid0 = blockIdx.x;
  const int bid = (bid0 & 7) * 512 + (bid0 >> 3);
  const int ct = bid & 3;
  const int mt = bid >> 2;
  const int m0 = mt * 128;
  const int c0 = ct * 128;
  const int t = threadIdx.x;
  const int l = t & 63;
  const int w = t >> 6;
  const int wr = w >> 1, wc = w & 1;
  const int lg = l >> 4, lr = l & 15;

  f32x4 ak[4][4] = {};
  f32x4 av[4][4] = {};

  // staging source mapping: wave writes 1KB linear = 16 rows x 64B.
  const int sr = l >> 2;                 // row within the 16-row group
  const int scg = (l & 3) ^ (sr & 3);    // inverse-swizzled 16B chunk index

  auto stage = [&](int buf, int k0) {
    #pragma unroll
    for (int q = 0; q < 2; ++q) {
      const int r0 = w * 32 + q * 16;
      const size_t soff = (size_t)(r0 + sr) * NDIM + k0 + scg * 8;
      gld16(&Xb[(size_t)m0 * NDIM + soff], (char*)&As[buf][r0 * 32]);
      gld16(&Wkb[(size_t)c0 * NDIM + soff], (char*)&Bks[buf][r0 * 32]);
      gld16(&Wvb[(size_t)c0 * NDIM + soff], (char*)&Bvs[buf][r0 * 32]);
    }
  };

  auto compute = [&](int buf) {
    bf16x8 a[4], bk_[4], bv_[4];
    #pragma unroll
    for (int i = 0; i < 4; ++i) {
      const int r = wr * 64 + i * 16 + lr;
      const int byte = r * 64 + ((lg ^ (r & 3)) * 16);
      a[i] = *reinterpret_cast<const bf16x8*>((const char*)&As[buf][0] + byte);
    }
    #pragma unroll
    for (int j = 0; j < 4; ++j) {
      const int r = wc * 64 + j * 16 + lr;
      const int byte = r * 64 + ((lg ^ (r & 3)) * 16);
      bk_[j] = *reinterpret_cast<const bf16x8*>((const char*)&Bks[buf][0] + byte);
      bv_[j] = *reinterpret_cast<const bf16x8*>((const char*)&Bvs[buf][0] + byte);
    }
    #pragma unroll
    for (int i = 0; i < 4; ++i) {
      #pragma unroll
      for (int j = 0; j < 4; ++j) {
        ak[i][j] = __builtin_amdgcn_mfma_f32_16x16x32_bf16(a[i], bk_[j], ak[i][j], 0, 0, 0);
        av[i][j] = __builtin_amdgcn_mfma_f32_16x16x32_bf16(a[i], bv_[j], av[i][j], 0, 0, 0);
      }
    }
  };

  stage(0, 0);
  __builtin_amdgcn_sched_barrier(0);
  for (int ts = 0; ts < 15; ++ts) {
    stage((ts + 1) & 1, (ts + 1) << 5);       // prefetch next tile
    asm volatile("s_waitcnt vmcnt(6)" ::: "memory");  // cur tile landed
    __builtin_amdgcn_s_barrier();
    compute(ts & 1);
    __builtin_amdgcn_s_barrier();             // readers done before overwrite
  }
  asm volatile("s_waitcnt vmcnt(0)" ::: "memory");
  __builtin_amdgcn_s_barrier();
  compute(1);                                  // ts=15 -> buf 1
  __builtin_amdgcn_sched_barrier(0);

  // C/D frag mapping: col = lane&15 (lr), row = 4*(lane>>4)+e per 16-block.
  // Global row R = m0 + wr*64 + i*16 + 4*lg + e -> seed s == e (base % 4 == 0).

  // ---- K epilogue: GMM log-likelihood ----
  {
    const float p0 = pp[0], p1 = pp[1], p2 = pp[2], p3 = pp[3];
    const float pmx = fmaxf(fmaxf(p0, p1), fmaxf(p2, p3));
    const float lse = pmx + logf(expf(p0 - pmx) + expf(p1 - pmx) + expf(p2 - pmx) + expf(p3 - pmx));
    const float lp[4] = {p0 - lse, p1 - lse, p2 - lse, p3 - lse};

    float part[4][4];
    #pragma unroll
    for (int i = 0; i < 4; ++i)
      #pragma unroll
      for (int e = 0; e < 4; ++e) part[i][e] = 0.f;

    #pragma unroll
    for (int j = 0; j < 4; ++j) {
      const int Jg = c0 + wc * 64 + j * 16 + lr;
      const float bj = bkp[Jg];
      #pragma unroll
      for (int e = 0; e < 4; ++e) {
        const float sv = Sp[e * NDIM + Jg];
        const float sig = log1pf(expf(sv));       // softplus
        const float mu = Mp[e * NDIM + Jg];
        const float cc = -0.5f * LOG2PI - logf(sig);
        const float i2 = 0.5f / (sig * sig);
        #pragma unroll
        for (int i = 0; i < 4; ++i) {
          const float kv = ak[i][j][e] + bj;
          const float d = kv - mu;
          part[i][e] += cc - d * d * i2;
        }
      }
    }
    #pragma unroll
    for (int off = 1; off < 16; off <<= 1) {
      #pragma unroll
      for (int i = 0; i < 4; ++i)
        #pragma unroll
        for (int e = 0; e < 4; ++e)
          part[i][e] += __shfl_xor(part[i][e], off, 64);
    }
    if (lr == 0) {
      const int h = ct * 2 + wc;
      #pragma unroll
      for (int i = 0; i < 4; ++i) {
        #pragma unroll
        for (int e = 0; e < 4; ++e) {
          const int R = m0 + wr * 64 + i * 16 + 4 * lg + e;
          const int bn = R >> 2;               // b*2048 + n
          const int bb = bn >> 11;
          const int nn = bn & (NN - 1);
          ll_ws[((size_t)((bb * NS + e) * NH + h)) * NN + nn] =
              (part[i][e] + lp[e]) * INV_SQRT_DIM;
        }
      }
    }
  }

  // ---- V epilogue: bf16 V in [g][n][d] ----
  {
    #pragma unroll
    for (int j = 0; j < 4; ++j) {
      const int Jg = c0 + wc * 64 + j * 16 + lr;
      const float bj = bvp[Jg];
      const int h = Jg >> 6;
      const int d = Jg & 63;
      #pragma unroll
      for (int i = 0; i < 4; ++i) {
        #pragma unroll
        for (int e = 0; e < 4; ++e) {
          const int R = m0 + wr * 64 + i * 16 + 4 * lg + e;
          const int bn = R >> 2;
          const int bb = bn >> 11;
          const int nn = bn & (NN - 1);
          v_ws[((size_t)((bb * NS + e) * NH + h) * NN + nn) * NDS + d] =
              f2bf(av[i][j][e] + bj);
        }
      }
    }
  }
}

// ---------------------------------------------------------------------------
// Fallback (ws too small for bf16 X): round-4 single-buffer structure,
// A reg-staged fp32->bf16 with swizzled ds_write, B via global_load_lds.
// ---------------------------------------------------------------------------
__global__ __launch_bounds__(256) void projkv_fb_kernel(
    const float* __restrict__ Xf,
    const short* __restrict__ Wkb, const short* __restrict__ Wvb,
    const float* __restrict__ bkp, const float* __restrict__ bvp,
    const float* __restrict__ Mp, const float* __restrict__ Sp,
    const float* __restrict__ pp,
    float* __restrict__ ll_ws, short* __restrict__ v_ws)
{
  __shared__ short As[128 * 64];
  __shared__ short Bks[128 * 64];
  __shared__ short Bvs[128 * 64];

  const int bid0 = blockIdx.x;
  const int bid = (bid0 & 7) * 512 + (bid0 >> 3);
  const int ct = bid & 3;
  const int mt = bid >> 2;
  const int m0 = mt * 128;
  const int c0 = ct * 128;
  const int t = threadIdx.x;
  const int l = t & 63;
  const int w = t >> 6;
  const int wr = w >> 1, wc = w & 1;
  const int lg = l >> 4, lr = l & 15;

  f32x4 ak[4][4] = {};
  f32x4 av[4][4] = {};

  const int srr = t >> 4;
  const int skv = t & 15;
  const int g8 = (l & 7) ^ (l >> 3);

  for (int k0 = 0; k0 < NDIM; k0 += 64) {
    __syncthreads();
    #pragma unroll
    for (int pass = 0; pass < 8; ++pass) {
      const int row = pass * 16 + srr;
      const int wb = (row * 128 + skv * 8) ^ ((row & 7) << 4);
      const float4 xa = *reinterpret_cast<const float4*>(
          &Xf[(size_t)(m0 + row) * NDIM + k0 + skv * 4]);
      short4 s;
      s.x = f2bf(xa.x); s.y = f2bf(xa.y); s.z = f2bf(xa.z); s.w = f2bf(xa.w);
      *reinterpret_cast<short4*>((char*)As + wb) = s;
    }
    #pragma unroll
    for (int q = 0; q < 4; ++q) {
      const int r0 = w * 32 + q * 8;
      const size_t gi = (size_t)(c0 + r0 + (l >> 3)) * NDIM + k0 + g8 * 8;
      gld16(&Wkb[gi], (char*)Bks + r0 * 128);
      gld16(&Wvb[gi], (char*)Bvs + r0 * 128);
    }
    __syncthreads();

    #pragma unroll
    for (int kk = 0; kk < 64; kk += 32) {
      bf16x8 a[4], bkf[4], bvf[4];
      #pragma unroll
      for (int i = 0; i < 4; ++i) {
        const int r = wr * 64 + i * 16 + lr;
        const int byte = (r * 128 + (kk + lg * 8) * 2) ^ ((r & 7) << 4);
        a[i] = *reinterpret_cast<const bf16x8*>((const char*)As + byte);
      }
      #pragma unroll
      for (int j = 0; j < 4; ++j) {
        const int r = wc * 64 + j * 16 + lr;
        const int byte = (r * 128 + (kk + lg * 8) * 2) ^ ((r & 7) << 4);
        bkf[j] = *reinterpret_cast<const bf16x8*>((const char*)Bks + byte);
        bvf[j] = *reinterpret_cast<const bf16x8*>((const char*)Bvs + byte);
      }
      #pragma unroll
      for (int i = 0; i < 4; ++i) {
        #pragma unroll
        for (int j = 0; j < 4; ++j) {
          ak[i][j] = __builtin_amdgcn_mfma_f32_16x16x32_bf16(a[i], bkf[j], ak[i][j], 0, 0, 0);
          av[i][j] = __builtin_amdgcn_mfma_f32_16x16x32_bf16(a[i], bvf[j], av[i][j], 0, 0, 0);
        }
      }
    }
  }

  {
    const float p0 = pp[0], p1 = pp[1], p2 = pp[2], p3 = pp[3];
    const float pmx = fmaxf(fmaxf(p0, p1), fmaxf(p2, p3));
    const float lse = pmx + logf(expf(p0 - pmx) + expf(p1 - pmx) + expf(p2 - pmx) + expf(p3 - pmx));
    const float lp[4] = {p0 - lse, p1 - lse, p2 - lse, p3 - lse};

    float part[4][4];
    #pragma unroll
    for (int i = 0; i < 4; ++i)
      #pragma unroll
      for (int e = 0; e < 4; ++e) part[i][e] = 0.f;

    #pragma unroll
    for (int j = 0; j < 4; ++j) {
      const int Jg = c0 + wc * 64 + j * 16 + lr;
      const float bj = bkp[Jg];
      #pragma unroll
      for (int e = 0; e < 4; ++e) {
        const float sv = Sp[e * NDIM + Jg];
        const float sig = log1pf(expf(sv));
        const float mu = Mp[e * NDIM + Jg];
        const float cc = -0.5f * LOG2PI - logf(sig);
        const float i2 = 0.5f / (sig * sig);
        #pragma unroll
        for (int i = 0; i < 4; ++i) {
          const float kv = ak[i][j][e] + bj;
          const float d = kv - mu;
          part[i][e] += cc - d * d * i2;
        }
      }
    }
    #pragma unroll
    for (int off = 1; off < 16; off <<= 1) {
      #pragma unroll
      for (int i = 0; i < 4; ++i)
        #pragma unroll
        for (int e = 0; e < 4; ++e)
          part[i][e] += __shfl_xor(part[i][e], off, 64);
    }
    if (lr == 0) {
      const int h = ct * 2 + wc;
      #pragma unroll
      for (int i = 0; i < 4; ++i) {
        #pragma unroll
        for (int e = 0; e < 4; ++e) {
          const int R = m0 + wr * 64 + i * 16 + 4 * lg + e;
          const int bn = R >> 2;
          const int bb = bn >> 11;
          const int nn = bn & (NN - 1);
          ll_ws[((size_t)((bb * NS + e) * NH + h)) * NN + nn] =
              (part[i][e] + lp[e]) * INV_SQRT_DIM;
        }
      }
    }
  }

  {
    #pragma unroll
    for (int j = 0; j < 4; ++j) {
      const int Jg = c0 + wc * 64 + j * 16 + lr;
      const float bj = bvp[Jg];
      const int h = Jg >> 6;
      const int d = Jg & 63;
      #pragma unroll
      for (int i = 0; i < 4; ++i) {
        #pragma unroll
        for (int e = 0; e < 4; ++e) {
          const int R = m0 + wr * 64 + i * 16 + 4 * lg + e;
          const int bn = R >> 2;
          const int bb = bn >> 11;
          const int nn = bn & (NN - 1);
          v_ws[((size_t)((bb * NS + e) * NH + h) * NN + nn) * NDS + d] =
              f2bf(av[i][j][e] + bj);
        }
      }
    }
  }
}

// ---------------------------------------------------------------------------
// Pooling: per g=(b*4+s)*8+h : A = softmax(ll[g,:]), O0[g,d] = mu + sum_n A_n V[g,n,d]
// ---------------------------------------------------------------------------
__global__ __launch_bounds__(256) void pool_kernel(
    const float* __restrict__ ll_ws, const short* __restrict__ v_ws,
    const float* __restrict__ Mp, float* __restrict__ O0)
{
  __shared__ float Al[NN];
  __shared__ float red[4][NDS];
  __shared__ float sred[8];
  const int g = blockIdx.x;
  const int t = threadIdx.x;
  const int w = t >> 6, l = t & 63;
  const float* ll = ll_ws + (size_t)g * NN;

  float v8[8];
  float mx = -1e30f;
  #pragma unroll
  for (int i = 0; i < 8; ++i) { v8[i] = ll[t + i * 256]; mx = fmaxf(mx, v8[i]); }
  #pragma unroll
  for (int off = 1; off < 64; off <<= 1) mx = fmaxf(mx, __shfl_xor(mx, off, 64));
  if (l == 0) sred[w] = mx;
  __syncthreads();
  mx = fmaxf(fmaxf(sred[0], sred[1]), fmaxf(sred[2], sred[3]));

  float sum = 0.f;
  #pragma unroll
  for (int i = 0; i < 8; ++i) {
    const float e = expf(v8[i] - mx);
    Al[t + i * 256] = e;
    sum += e;
  }
  #pragma unroll
  for (int off = 1; off < 64; off <<= 1) sum += __shfl_xor(sum, off, 64);
  __syncthreads();
  if (l == 0) sred[4 + w] = sum;
  __syncthreads();
  const float lsum = sred[4] + sred[5] + sred[6] + sred[7];

  const short* vp = v_ws + (size_t)g * ((size_t)NN * NDS) + l;
  float acc = 0.f;
  #pragma unroll 8
  for (int i = 0; i < 512; ++i) {
    const int n = (w << 9) + i;
    acc += Al[n] * bf2f(vp[(size_t)n * NDS]);
  }
  red[w][l] = acc;
  __syncthreads();
  if (w == 0) {
    const float tot = red[0][l] + red[1][l] + red[2][l] + red[3][l];
    const int s = (g >> 3) & 3, h = g & 7;
    O0[(size_t)g * NDS + l] = Mp[s * NDIM + h * NDS + l] + tot / lsum;
  }
}

// ---------------------------------------------------------------------------
// BatchNorm1d (training mode, biased var, eps=1e-5) over B=16 per feature f.
// ---------------------------------------------------------------------------
__global__ __launch_bounds__(256) void bn_kernel(
    const float* __restrict__ Xin, const float* __restrict__ gg,
    const float* __restrict__ bb, float* __restrict__ Yo)
{
  const int f = blockIdx.x * 256 + threadIdx.x;  // 0..2047
  float x[NB];
  float m = 0.f;
  #pragma unroll
  for (int b = 0; b < NB; ++b) { x[b] = Xin[b * (NS * NDIM) + f]; m += x[b]; }
  m *= (1.f / NB);
  float v = 0.f;
  #pragma unroll
  for (int b = 0; b < NB; ++b) { const float d = x[b] - m; v += d * d; }
  v *= (1.f / NB);
  const float inv = rsqrtf(v + 1e-5f) * gg[f];
  const float bf = bb[f];
  #pragma unroll
  for (int b = 0; b < NB; ++b) Yo[b * (NS * NDIM) + f] = (x[b] - m) * inv + bf;
}

// ---------------------------------------------------------------------------
// Z = Y + relu(Y @ Wo^T + bo), rows = 64, cols = 512
// ---------------------------------------------------------------------------
__global__ __launch_bounds__(256) void mlp_kernel(
    const float* __restrict__ Yi, const float* __restrict__ Wo,
    const float* __restrict__ bo, float* __restrict__ Zo)
{
  const int idx = blockIdx.x * 256 + threadIdx.x;  // 0..32767
  const int r = idx >> 9, j = idx & 511;
  const float4* yr = reinterpret_cast<const float4*>(Yi + (size_t)r * NDIM);
  const float4* wrow = reinterpret_cast<const float4*>(Wo + (size_t)j * NDIM);
  float acc = 0.f;
  #pragma unroll 4
  for (int i = 0; i < NDIM / 4; ++i) {
    const float4 a = yr[i], b = wrow[i];
    acc += a.x * b.x + a.y * b.y + a.z * b.z + a.w * b.w;
  }
  const float rl = acc + bo[j];
  Zo[idx] = Yi[idx] + fmaxf(rl, 0.f);
}

extern "C" void kernel_launch(void* const* d_in, const int* in_sizes, int n_in,
                              void* d_out, int out_size, void* d_ws, size_t ws_size,
                              hipStream_t stream) {
  (void)in_sizes; (void)n_in; (void)out_size;
  const float* X  = (const float*)d_in[0];
  const float* M  = (const float*)d_in[1];
  const float* S  = (const float*)d_in[2];
  const float* p  = (const float*)d_in[3];
  const float* Wk = (const float*)d_in[4];
  const float* bk = (const float*)d_in[5];
  const float* Wv = (const float*)d_in[6];
  const float* bv = (const float*)d_in[7];
  const float* Wo = (const float*)d_in[8];
  const float* bo = (const float*)d_in[9];
  const float* g0 = (const float*)d_in[10];
  const float* b0 = (const float*)d_in[11];
  const float* g1 = (const float*)d_in[12];
  const float* b1 = (const float*)d_in[13];

  char* ws = (char*)d_ws;
  short* v_ws  = (short*)ws;                                    // 128 MiB bf16 V
  float* ll_ws = (float*)(ws + (size_t)134217728);              // 4 MiB logits
  float* O0    = (float*)(ws + (size_t)138412032);              // 128 KiB
  float* Y     = O0 + 32768;
  float* Z     = Y + 32768;
  short* Wkb   = (short*)(ws + (size_t)138805248);              // 512 KiB
  short* Wvb   = (short*)(ws + (size_t)139329536);              // 512 KiB
  short* Xb    = (short*)(ws + (size_t)139853824);              // 128 MiB (big path)
  const bool big = ws_size >= (size_t)139853824 + 134217728;

  cvtw_kernel<<<256, 256, 0, stream>>>(Wk, Wv, Wkb, Wvb);
  if (big) {
    cvtx_kernel<<<2048, 256, 0, stream>>>(X, Xb, 8388608);
    projkv2_kernel<<<4096, 256, 0, stream>>>(Xb, Wkb, Wvb, bk, bv, M, S, p, ll_ws, v_ws);
  } else {
    projkv_fb_kernel<<<4096, 256, 0, stream>>>(X, Wkb, Wvb, bk, bv, M, S, p, ll_ws, v_ws);
  }
  pool_kernel<<<512, 256, 0, stream>>>(ll_ws, v_ws, M, O0);
  bn_kernel<<<8, 256, 0, stream>>>(O0, g0, b0, Y);
  mlp_kernel<<<128, 256, 0, stream>>>(Y, Wo, bo, Z);
  bn_kernel<<<8, 256, 0, stream>>>(Z, g1, b1, (float*)d_out);
}